// Round 14
// baseline (527.336 us; speedup 1.0000x reference)
//
#include <hip/hip_runtime.h>

typedef short short8 __attribute__((ext_vector_type(8)));
typedef float floatx4 __attribute__((ext_vector_type(4)));

constexpr int N_PIX  = 16384;           // 4*64*64 pixels
constexpr int FEAT_N = N_PIX * 256;     // floats per feat buffer
constexpr int OFF_N  = N_PIX * 18;
constexpr int KDIM   = 2304;
constexpr int WB_L   = 2304 * 256;      // bf16 elems per deform layer
constexpr int WTO_L  = KDIM * 18;       // fp32 elems per offset layer

__device__ __forceinline__ unsigned short bf16_rn(float v) {
  unsigned u = __float_as_uint(v);
  return (unsigned short)((u + 0x7FFFu + ((u >> 16) & 1u)) >> 16);
}
__device__ __forceinline__ void split_bf16(float v, short& h, short& l) {
  unsigned short hu = bf16_rn(v);
  float hf = __uint_as_float(((unsigned)hu) << 16);
  h = (short)hu;
  l = (short)bf16_rn(v - hf);
}

// ---------------- concat [x;y] NCHW -> feat NHWC (fp32) ----------------
__global__ __launch_bounds__(256) void concat_nhwc(const float* __restrict__ x,
                                                   const float* __restrict__ y,
                                                   float* __restrict__ feat) {
  __shared__ float tile[64][65];
  int bid = blockIdx.x;                 // b*256 + h*4 + ct
  int ct = bid & 3, h = (bid >> 2) & 63, b = bid >> 8;
  int c0 = ct * 64;
  const float* src = (c0 < 128) ? x : y;
  int cs = c0 & 127;
  int t = threadIdx.x;
  int w = t & 63, cl = t >> 6;
#pragma unroll
  for (int i = 0; i < 16; ++i) {
    int c = cl + i * 4;
    tile[c][w] = src[((b * 128 + cs + c) * 64 + h) * 64 + w];
  }
  __syncthreads();
  int c2 = t & 63, wl = t >> 6;
#pragma unroll
  for (int i = 0; i < 16; ++i) {
    int w2 = wl + i * 4;
    feat[((b * 64 + h) * 64 + w2) * 256 + c0 + c2] = tile[c2][w2];
  }
}

// ------------- weight prep: deform_w -> MFMA-fragment-linear hi/lo bf16 -------------
__global__ __launch_bounds__(256) void prep_wb(const float* __restrict__ dw,
                                               unsigned short* __restrict__ wbh,
                                               unsigned short* __restrict__ wbl) {
  int g = blockIdx.x * 256 + threadIdx.x;      // < 3*WB_L
  int l = g / WB_L, r = g % WB_L;
  int j = r & 7, lane = (r >> 3) & 63, nt = (r >> 9) & 15, kc = r >> 13;
  int k = kc * 32 + (lane >> 4) * 8 + j;
  int o = nt * 16 + (lane & 15);
  float w = dw[((l * 256 + o) * 256 + (k & 255)) * 9 + (k >> 8)];
  short h, lo; split_bf16(w, h, lo);
  wbh[g] = (unsigned short)h; wbl[g] = (unsigned short)lo;
}

// offset_w [4][18(o)][256(i)][3][3] -> wto[l][(tap*256+i)*18 + o]  (fp32)
__global__ __launch_bounds__(256) void t_ow(const float* __restrict__ ow,
                                            float* __restrict__ wto) {
  int g = blockIdx.x * 256 + threadIdx.x;      // < 4*41472
  int l = g / WTO_L, r = g % WTO_L;
  int o = r % 18, k = r / 18;
  int i = k & 255, tap = k >> 8;
  wto[g] = ow[(l * 18 + o) * KDIM + i * 9 + tap];
}

// ---------------- partial-sum folds (float4) ----------------
__global__ __launch_bounds__(256) void addf(float* __restrict__ a,
                                            const float* __restrict__ b) {
  int i = (blockIdx.x * 256 + threadIdx.x) * 4;
  float4 va = *(const float4*)(a + i);
  float4 vb = *(const float4*)(b + i);
  va.x += vb.x; va.y += vb.y; va.z += vb.z; va.w += vb.w;
  *(float4*)(a + i) = va;
}
__global__ __launch_bounds__(256) void addf2o(float* __restrict__ a,
                                              const float* __restrict__ b,
                                              const float* __restrict__ c) {
  int i = (blockIdx.x * 256 + threadIdx.x) * 4;
  float4 va = *(const float4*)(a + i);
  float4 vb = *(const float4*)(b + i);
  float4 vc = *(const float4*)(c + i);
  va.x += vb.x + vc.x; va.y += vb.y + vc.y;
  va.z += vb.z + vc.z; va.w += vb.w + vc.w;
  *(float4*)(a + i) = va;
}

// ---------------- offset conv (3x3 SAME, 256 -> 18) — K-split x3 across blocks ----
// Grid 768: r_ = bid & 255 -> XCD-chunked pg; third = bid >> 8 (0..2). Wave wid
// does chunks (third*8 + wid)*6 .. +6 (24 wave-slots x 6 = 144 = full K; exact
// split of R13's 9-chunk sub-chains' parent — kc-range class, passed R4/R8/R13).
// Block structure (8 waves, single barrier, 8-way reduce) identical to R13's.
template <bool NCHW>
__global__ __launch_bounds__(512) void off_conv(const float* __restrict__ feat,
                                                const float* __restrict__ wo,
                                                float* __restrict__ o0,
                                                float* __restrict__ o1,
                                                float* __restrict__ o2) {
  __shared__ float red[512][19];
  int t = threadIdx.x;
  int lane = t & 63;
  int wid = __builtin_amdgcn_readfirstlane(t >> 6);   // wave 0..7
  const int r_  = blockIdx.x & 255;
  const int pg  = (r_ & 7) * 32 + (r_ >> 3);          // XCD-chunked, bijective
  const int third = blockIdx.x >> 8;                  // K-third
  int p = pg * 64 + lane;
  int b = p >> 12, h = (p >> 6) & 63, w = p & 63;
  float acc[18] = {};
  const int cb = (third * 8 + wid) * 6;
  for (int kc = cb; kc < cb + 6; ++kc) {
    int k0 = kc * 16;
    int tap = k0 >> 8, c0 = k0 & 255;
    int y = h + tap / 3 - 1, xx = w + tap % 3 - 1;
    float a[16];
#pragma unroll
    for (int q = 0; q < 16; ++q) a[q] = 0.f;
    if ((unsigned)y < 64u && (unsigned)xx < 64u) {
      const float4* srcp =
          (const float4*)(feat + ((b * 64 + y) * 64 + xx) * 256 + c0);
#pragma unroll
      for (int q = 0; q < 4; ++q) {
        float4 v = srcp[q];
        a[q * 4 + 0] = v.x; a[q * 4 + 1] = v.y;
        a[q * 4 + 2] = v.z; a[q * 4 + 3] = v.w;
      }
    }
    const float* wp = wo + k0 * 18;   // wave-uniform -> scalar loads
#pragma unroll
    for (int kk = 0; kk < 16; ++kk)
#pragma unroll
      for (int o = 0; o < 18; ++o)
        acc[o] += a[kk] * wp[kk * 18 + o];
  }
#pragma unroll
  for (int o = 0; o < 18; ++o) red[t][o] = acc[o];
  __syncthreads();
  if (t < 64) {
    float* outp = (third == 0) ? o0 : (third == 1 ? o1 : o2);
#pragma unroll
    for (int o = 0; o < 18; ++o) {
      float s = 0.f;
#pragma unroll
      for (int sg = 0; sg < 8; ++sg) s += red[lane + 64 * sg][o];
      if (NCHW)
        outp[(b * 18 + o) * 4096 + (p & 4095)] = s;
      else
        outp[p * 18 + o] = s;
    }
  }
}

// ---------------- deform conv — R12 ping-pong + B-register prefetch (2x unroll) ----
// ONLY change vs R12: the 8 B-loads for chunk kc+1 are ISSUED during chunk kc's
// phase (named sets bhA/blA, bhB/blB; 36 chunks even -> clean 2x unroll). Same B
// values feed the same MFMAs in the same order -> numerics bit-identical; load
// timing only (R6-proven-safe edit class).
__global__ __launch_bounds__(256) void deform_mfma(
    const float* __restrict__ feat, const float* __restrict__ off,
    const unsigned short* __restrict__ wbh, const unsigned short* __restrict__ wbl,
    float* __restrict__ out0, float* __restrict__ out1) {
  __shared__ __align__(16) unsigned short Ah[2][64 * 32], Al[2][64 * 32];
  __shared__ float cy[9][64], cx[9][64];
  const int t = threadIdx.x;
  const int r_  = blockIdx.x & 255;
  const int pg  = (r_ & 7) * 32 + (r_ >> 3);   // XCD-chunked, bijective on [0,256)
  const int pbase = pg * 64;
  const int half  = blockIdx.x >> 8;           // K-half: chunks [36h, 36h+36)
  const int bimg = pbase >> 12, h = (pbase >> 6) & 63;
  const float* fbase = feat + bimg * (4096 * 256);

  {  // sampling coords per (tap, pixel)
    int m = t & 63, p = pbase + m;
    for (int tap = t >> 6; tap < 9; tap += 4) {
      cy[tap][m] = off[p * 18 + 2 * tap]     + (float)(tap / 3 - 1 + h);
      cx[tap][m] = off[p * 18 + 2 * tap + 1] + (float)(tap % 3 - 1 + m);
    }
  }
  __syncthreads();

  const int m  = t & 63;                       // gather pixel
  const int cg = t >> 6;                       // gather channel-group (8 ch)
  const int lane = t & 63;
  const int wv = __builtin_amdgcn_readfirstlane(t >> 6);
  const int awoff = ((m >> 4) * 64 + cg * 16 + (m & 15)) * 8;  // frag-linear A slot

  floatx4 acc[4][4];
  const floatx4 z4 = {0.f, 0.f, 0.f, 0.f};
#pragma unroll
  for (int i = 0; i < 4; ++i)
#pragma unroll
    for (int jn = 0; jn < 4; ++jn) acc[i][jn] = z4;

  // ---- calibration MFMA: measure the true C/D slot map ----
  int rowmap[4], colmap[4];
  {
    short8 cA, cB;
    int own = lane & 15, q = (lane >> 4) & 3;
#pragma unroll
    for (int j = 0; j < 8; ++j) {
      int k = q * 8 + j;                     // assumed k-slot id (shared-perm safe)
      cA[j] = (short)((k == own) ? bf16_rn(1.0f) : 0);
      cB[j] = (short)((k < 16) ? bf16_rn((float)(k * 16 + own)) : 0);
    }
    floatx4 cal = __builtin_amdgcn_mfma_f32_16x16x32_bf16(cA, cB, z4, 0, 0, 0);
#pragma unroll
    for (int r = 0; r < 4; ++r) {
      int v = (int)(cal[r] + 0.5f);          // exact integer in [0,255]
      rowmap[r] = (v >> 4) & 15;
      colmap[r] = v & 15;
    }
  }

  const short8* BH = (const short8*)wbh;
  const short8* BL = (const short8*)wbl;

  float4 pf[8];
  float w4[4];
  auto issue = [&](int kc) {
    int tap = kc >> 3, c0 = (kc & 7) * 32 + cg * 8;
    float py = cy[tap][m], px = cx[tap][m];
    float fy = floorf(py), fx = floorf(px);
    int iy = (int)fy, ix = (int)fx;
    float wy1 = py - fy, wx1 = px - fx;
    float wy0 = 1.f - wy1, wx0 = 1.f - wx1;
    w4[0] = wy0 * wx0; w4[1] = wy0 * wx1; w4[2] = wy1 * wx0; w4[3] = wy1 * wx1;
#pragma unroll
    for (int c = 0; c < 4; ++c) {
      int yy = iy + (c >> 1), xx = ix + (c & 1);
      bool ok = ((unsigned)yy < 64u) && ((unsigned)xx < 64u);
      if (!ok) w4[c] = 0.f;
      int yc = min(max(yy, 0), 63), xc = min(max(xx, 0), 63);
      const float4* p = (const float4*)(fbase + (yc * 64 + xc) * 256 + c0);
      pf[c * 2]     = p[0];
      pf[c * 2 + 1] = p[1];
    }
  };
  auto loadB = [&](int kc, short8 (&bh)[4], short8 (&bl)[4]) {
#pragma unroll
    for (int ni = 0; ni < 4; ++ni) {
      int bidx = (kc * 16 + wv * 4 + ni) * 64 + lane;
      bh[ni] = BH[bidx];
      bl[ni] = BL[bidx];
    }
  };
  auto combine_stage = [&](int buf) {
    const float* pfp = (const float*)pf;
    short8 hv, lv;
#pragma unroll
    for (int j = 0; j < 8; ++j) {
      float v = w4[0] * pfp[j] + w4[1] * pfp[8 + j] + w4[2] * pfp[16 + j] +
                w4[3] * pfp[24 + j];
      short hh, ll; split_bf16(v, hh, ll);
      hv[j] = hh; lv[j] = ll;
    }
    *(short8*)&Ah[buf][awoff] = hv;
    *(short8*)&Al[buf][awoff] = lv;
  };
  auto mfma16 = [&](int buf, const short8 (&bh)[4], const short8 (&bl)[4]) {
    short8 ah[4], al[4];
#pragma unroll
    for (int mi = 0; mi < 4; ++mi) {
      ah[mi] = *(const short8*)&Ah[buf][(mi * 64 + lane) * 8];
      al[mi] = *(const short8*)&Al[buf][(mi * 64 + lane) * 8];
    }
#pragma unroll
    for (int mi = 0; mi < 4; ++mi)
#pragma unroll
      for (int ni = 0; ni < 4; ++ni) {
        acc[mi][ni] = __builtin_amdgcn_mfma_f32_16x16x32_bf16(ah[mi], bh[ni], acc[mi][ni], 0, 0, 0);
        acc[mi][ni] = __builtin_amdgcn_mfma_f32_16x16x32_bf16(ah[mi], bl[ni], acc[mi][ni], 0, 0, 0);
        acc[mi][ni] = __builtin_amdgcn_mfma_f32_16x16x32_bf16(al[mi], bh[ni], acc[mi][ni], 0, 0, 0);
      }
  };

  const int kcBeg = half * 36, kcEnd = kcBeg + 36;
  short8 bhA[4], blA[4], bhB[4], blB[4];

  // prologue: gather + combine + stage chunk kcBeg into buffer 0; B(kcBeg) -> set A
  issue(kcBeg);
  combine_stage(0);
  loadB(kcBeg, bhA, blA);
  __syncthreads();

  // 2x-unrolled main loop: 36 chunks, buffers/B-sets alternate deterministically.
  // even chunk kc: buf0->MFMA(setA), prefetch B(kc+1)->setB, stage kc+1->buf1
  // odd  chunk kc+1: buf1->MFMA(setB), prefetch B(kc+2)->setA, stage kc+2->buf0
  for (int kc = kcBeg; kc < kcEnd; kc += 2) {
    // ---- even step ----
    issue(kc + 1);                     // gathers for kc+1
    loadB(kc + 1, bhB, blB);           // prefetch B for kc+1 (consumed next step)
    mfma16(0, bhA, blA);               // MFMA chunk kc
    combine_stage(1);                  // stage kc+1
    __syncthreads();
    // ---- odd step ----
    if (kc + 2 < kcEnd) {
      issue(kc + 2);                   // gathers for kc+2
      loadB(kc + 2, bhA, blA);         // prefetch B for kc+2
    }
    mfma16(1, bhB, blB);               // MFMA chunk kc+1
    if (kc + 2 < kcEnd) combine_stage(0);
    __syncthreads();
  }

  // epilogue: use the MEASURED C/D map -> NHWC fp32 partial for this K-half
  float* o = half ? out1 : out0;
#pragma unroll
  for (int mi = 0; mi < 4; ++mi)
#pragma unroll
    for (int ni = 0; ni < 4; ++ni)
#pragma unroll
      for (int r = 0; r < 4; ++r) {
        int pgx = pbase + mi * 16 + rowmap[r];
        o[pgx * 256 + wv * 64 + ni * 16 + colmap[r]] = acc[mi][ni][r];
      }
}

// ---------------- launcher ----------------
extern "C" void kernel_launch(void* const* d_in, const int* in_sizes, int n_in,
                              void* d_out, int out_size, void* d_ws, size_t ws_size,
                              hipStream_t stream) {
  const float* x  = (const float*)d_in[0];
  const float* y  = (const float*)d_in[1];
  const float* ow = (const float*)d_in[2];   // [4][18][256][3][3]
  const float* dw = (const float*)d_in[3];   // [3][256][256][3][3]
  float* out = (float*)d_out;

  float* fA      = (float*)d_ws;
  float* fB      = fA + FEAT_N;
  float* off_buf = fB + FEAT_N;
  float* wto     = off_buf + OFF_N;          // 4 * WTO_L fp32
  unsigned short* wbh = (unsigned short*)(wto + 4 * WTO_L);
  unsigned short* wbl = wbh + 3 * WB_L;
  float* pscr    = (float*)(wbl + 3 * WB_L); // deform K-half-1 partial (FEAT_N)
  float* oscr1   = pscr + FEAT_N;            // off_conv K-third-1 partial (OFF_N)
  float* oscr2   = oscr1 + OFF_N;            // off_conv K-third-2 partial (OFF_N)
  // total ~62 MB; ws_size >= ~93 MB proven by R10's NQ=4 run.

  concat_nhwc<<<dim3(1024), dim3(256), 0, stream>>>(x, y, fA);
  prep_wb<<<dim3(3 * WB_L / 256), dim3(256), 0, stream>>>(dw, wbh, wbl);
  t_ow<<<dim3(4 * WTO_L / 256), dim3(256), 0, stream>>>(ow, wto);

  float* cur = fA;
  float* nxt = fB;
  for (int i = 0; i < 3; ++i) {
    off_conv<false><<<dim3(768), dim3(512), 0, stream>>>(cur, wto + i * WTO_L,
                                                         off_buf, oscr1, oscr2);
    addf2o<<<dim3(OFF_N / 4 / 256), dim3(256), 0, stream>>>(off_buf, oscr1,
                                                            oscr2);
    deform_mfma<<<dim3(512), dim3(256), 0, stream>>>(
        cur, off_buf, wbh + i * WB_L, wbl + i * WB_L, nxt, pscr);
    addf<<<dim3(FEAT_N / 4 / 256), dim3(256), 0, stream>>>(nxt, pscr);
    float* tmp = cur; cur = nxt; nxt = tmp;
  }
  off_conv<true><<<dim3(768), dim3(512), 0, stream>>>(cur, wto + 3 * WTO_L, out,
                                                      oscr1, oscr2);
  addf2o<<<dim3(OFF_N / 4 / 256), dim3(256), 0, stream>>>(out, oscr1, oscr2);
}

// Round 15
// 471.059 us; speedup vs baseline: 1.1195x; 1.1195x over previous
//
#include <hip/hip_runtime.h>

typedef short short8 __attribute__((ext_vector_type(8)));
typedef float floatx4 __attribute__((ext_vector_type(4)));

constexpr int N_PIX  = 16384;           // 4*64*64 pixels
constexpr int FEAT_N = N_PIX * 256;     // floats per feat buffer
constexpr int OFF_N  = N_PIX * 18;
constexpr int KDIM   = 2304;
constexpr int WB_L   = 2304 * 256;      // bf16 elems per deform layer
constexpr int WTO_L  = KDIM * 18;       // fp32 elems per offset layer

__device__ __forceinline__ unsigned short bf16_rn(float v) {
  unsigned u = __float_as_uint(v);
  return (unsigned short)((u + 0x7FFFu + ((u >> 16) & 1u)) >> 16);
}
__device__ __forceinline__ void split_bf16(float v, short& h, short& l) {
  unsigned short hu = bf16_rn(v);
  float hf = __uint_as_float(((unsigned)hu) << 16);
  h = (short)hu;
  l = (short)bf16_rn(v - hf);
}

// ---------------- concat [x;y] NCHW -> feat NHWC (fp32) ----------------
__global__ __launch_bounds__(256) void concat_nhwc(const float* __restrict__ x,
                                                   const float* __restrict__ y,
                                                   float* __restrict__ feat) {
  __shared__ float tile[64][65];
  int bid = blockIdx.x;                 // b*256 + h*4 + ct
  int ct = bid & 3, h = (bid >> 2) & 63, b = bid >> 8;
  int c0 = ct * 64;
  const float* src = (c0 < 128) ? x : y;
  int cs = c0 & 127;
  int t = threadIdx.x;
  int w = t & 63, cl = t >> 6;
#pragma unroll
  for (int i = 0; i < 16; ++i) {
    int c = cl + i * 4;
    tile[c][w] = src[((b * 128 + cs + c) * 64 + h) * 64 + w];
  }
  __syncthreads();
  int c2 = t & 63, wl = t >> 6;
#pragma unroll
  for (int i = 0; i < 16; ++i) {
    int w2 = wl + i * 4;
    feat[((b * 64 + h) * 64 + w2) * 256 + c0 + c2] = tile[c2][w2];
  }
}

// ------------- weight prep: deform_w -> MFMA-fragment-linear hi/lo bf16 -------------
__global__ __launch_bounds__(256) void prep_wb(const float* __restrict__ dw,
                                               unsigned short* __restrict__ wbh,
                                               unsigned short* __restrict__ wbl) {
  int g = blockIdx.x * 256 + threadIdx.x;      // < 3*WB_L
  int l = g / WB_L, r = g % WB_L;
  int j = r & 7, lane = (r >> 3) & 63, nt = (r >> 9) & 15, kc = r >> 13;
  int k = kc * 32 + (lane >> 4) * 8 + j;
  int o = nt * 16 + (lane & 15);
  float w = dw[((l * 256 + o) * 256 + (k & 255)) * 9 + (k >> 8)];
  short h, lo; split_bf16(w, h, lo);
  wbh[g] = (unsigned short)h; wbl[g] = (unsigned short)lo;
}

// offset_w [4][18(o)][256(i)][3][3] -> wto[l][(tap*256+i)*18 + o]  (fp32)
__global__ __launch_bounds__(256) void t_ow(const float* __restrict__ ow,
                                            float* __restrict__ wto) {
  int g = blockIdx.x * 256 + threadIdx.x;      // < 4*41472
  int l = g / WTO_L, r = g % WTO_L;
  int o = r % 18, k = r / 18;
  int i = k & 255, tap = k >> 8;
  wto[g] = ow[(l * 18 + o) * KDIM + i * 9 + tap];
}

// ---------------- partial-sum folds (float4) ----------------
__global__ __launch_bounds__(256) void addf(float* __restrict__ a,
                                            const float* __restrict__ b) {
  int i = (blockIdx.x * 256 + threadIdx.x) * 4;
  float4 va = *(const float4*)(a + i);
  float4 vb = *(const float4*)(b + i);
  va.x += vb.x; va.y += vb.y; va.z += vb.z; va.w += vb.w;
  *(float4*)(a + i) = va;
}
__global__ __launch_bounds__(256) void addf2o(float* __restrict__ a,
                                              const float* __restrict__ b,
                                              const float* __restrict__ c) {
  int i = (blockIdx.x * 256 + threadIdx.x) * 4;
  float4 va = *(const float4*)(a + i);
  float4 vb = *(const float4*)(b + i);
  float4 vc = *(const float4*)(c + i);
  va.x += vb.x + vc.x; va.y += vb.y + vc.y;
  va.z += vb.z + vc.z; va.w += vb.w + vc.w;
  *(float4*)(a + i) = va;
}

// ---------------- offset conv (3x3 SAME, 256 -> 18) — K-split x3 (R14-verified) ----
template <bool NCHW>
__global__ __launch_bounds__(512) void off_conv(const float* __restrict__ feat,
                                                const float* __restrict__ wo,
                                                float* __restrict__ o0,
                                                float* __restrict__ o1,
                                                float* __restrict__ o2) {
  __shared__ float red[512][19];
  int t = threadIdx.x;
  int lane = t & 63;
  int wid = __builtin_amdgcn_readfirstlane(t >> 6);   // wave 0..7
  const int r_  = blockIdx.x & 255;
  const int pg  = (r_ & 7) * 32 + (r_ >> 3);          // XCD-chunked, bijective
  const int third = blockIdx.x >> 8;                  // K-third
  int p = pg * 64 + lane;
  int b = p >> 12, h = (p >> 6) & 63, w = p & 63;
  float acc[18] = {};
  const int cb = (third * 8 + wid) * 6;
  for (int kc = cb; kc < cb + 6; ++kc) {
    int k0 = kc * 16;
    int tap = k0 >> 8, c0 = k0 & 255;
    int y = h + tap / 3 - 1, xx = w + tap % 3 - 1;
    float a[16];
#pragma unroll
    for (int q = 0; q < 16; ++q) a[q] = 0.f;
    if ((unsigned)y < 64u && (unsigned)xx < 64u) {
      const float4* srcp =
          (const float4*)(feat + ((b * 64 + y) * 64 + xx) * 256 + c0);
#pragma unroll
      for (int q = 0; q < 4; ++q) {
        float4 v = srcp[q];
        a[q * 4 + 0] = v.x; a[q * 4 + 1] = v.y;
        a[q * 4 + 2] = v.z; a[q * 4 + 3] = v.w;
      }
    }
    const float* wp = wo + k0 * 18;   // wave-uniform -> scalar loads
#pragma unroll
    for (int kk = 0; kk < 16; ++kk)
#pragma unroll
      for (int o = 0; o < 18; ++o)
        acc[o] += a[kk] * wp[kk * 18 + o];
  }
#pragma unroll
  for (int o = 0; o < 18; ++o) red[t][o] = acc[o];
  __syncthreads();
  if (t < 64) {
    float* outp = (third == 0) ? o0 : (third == 1 ? o1 : o2);
#pragma unroll
    for (int o = 0; o < 18; ++o) {
      float s = 0.f;
#pragma unroll
      for (int sg = 0; sg < 8; ++sg) s += red[lane + 64 * sg][o];
      if (NCHW)
        outp[(b * 18 + o) * 4096 + (p & 4095)] = s;
      else
        outp[p * 18 + o] = s;
    }
  }
}

// ---------------- deform conv — R12/R13-EXACT single-barrier ping-pong ----------------
// (B-register-prefetch class closed: regressed in both R6 and R14 structures.)
__global__ __launch_bounds__(256) void deform_mfma(
    const float* __restrict__ feat, const float* __restrict__ off,
    const unsigned short* __restrict__ wbh, const unsigned short* __restrict__ wbl,
    float* __restrict__ out0, float* __restrict__ out1) {
  __shared__ __align__(16) unsigned short Ah[2][64 * 32], Al[2][64 * 32];
  __shared__ float cy[9][64], cx[9][64];
  const int t = threadIdx.x;
  const int r_  = blockIdx.x & 255;
  const int pg  = (r_ & 7) * 32 + (r_ >> 3);   // XCD-chunked, bijective on [0,256)
  const int pbase = pg * 64;
  const int half  = blockIdx.x >> 8;           // K-half: chunks [36h, 36h+36)
  const int bimg = pbase >> 12, h = (pbase >> 6) & 63;
  const float* fbase = feat + bimg * (4096 * 256);

  {  // sampling coords per (tap, pixel)
    int m = t & 63, p = pbase + m;
    for (int tap = t >> 6; tap < 9; tap += 4) {
      cy[tap][m] = off[p * 18 + 2 * tap]     + (float)(tap / 3 - 1 + h);
      cx[tap][m] = off[p * 18 + 2 * tap + 1] + (float)(tap % 3 - 1 + m);
    }
  }
  __syncthreads();

  const int m  = t & 63;                       // gather pixel
  const int cg = t >> 6;                       // gather channel-group (8 ch)
  const int lane = t & 63;
  const int wv = __builtin_amdgcn_readfirstlane(t >> 6);
  const int awoff = ((m >> 4) * 64 + cg * 16 + (m & 15)) * 8;  // frag-linear A slot

  floatx4 acc[4][4];
  const floatx4 z4 = {0.f, 0.f, 0.f, 0.f};
#pragma unroll
  for (int i = 0; i < 4; ++i)
#pragma unroll
    for (int jn = 0; jn < 4; ++jn) acc[i][jn] = z4;

  // ---- calibration MFMA: measure the true C/D slot map ----
  int rowmap[4], colmap[4];
  {
    short8 cA, cB;
    int own = lane & 15, q = (lane >> 4) & 3;
#pragma unroll
    for (int j = 0; j < 8; ++j) {
      int k = q * 8 + j;                     // assumed k-slot id (shared-perm safe)
      cA[j] = (short)((k == own) ? bf16_rn(1.0f) : 0);
      cB[j] = (short)((k < 16) ? bf16_rn((float)(k * 16 + own)) : 0);
    }
    floatx4 cal = __builtin_amdgcn_mfma_f32_16x16x32_bf16(cA, cB, z4, 0, 0, 0);
#pragma unroll
    for (int r = 0; r < 4; ++r) {
      int v = (int)(cal[r] + 0.5f);          // exact integer in [0,255]
      rowmap[r] = (v >> 4) & 15;
      colmap[r] = v & 15;
    }
  }

  const short8* BH = (const short8*)wbh;
  const short8* BL = (const short8*)wbl;

  float4 pf[8];
  float w4[4];
  auto issue = [&](int kc) {
    int tap = kc >> 3, c0 = (kc & 7) * 32 + cg * 8;
    float py = cy[tap][m], px = cx[tap][m];
    float fy = floorf(py), fx = floorf(px);
    int iy = (int)fy, ix = (int)fx;
    float wy1 = py - fy, wx1 = px - fx;
    float wy0 = 1.f - wy1, wx0 = 1.f - wx1;
    w4[0] = wy0 * wx0; w4[1] = wy0 * wx1; w4[2] = wy1 * wx0; w4[3] = wy1 * wx1;
#pragma unroll
    for (int c = 0; c < 4; ++c) {
      int yy = iy + (c >> 1), xx = ix + (c & 1);
      bool ok = ((unsigned)yy < 64u) && ((unsigned)xx < 64u);
      if (!ok) w4[c] = 0.f;
      int yc = min(max(yy, 0), 63), xc = min(max(xx, 0), 63);
      const float4* p = (const float4*)(fbase + (yc * 64 + xc) * 256 + c0);
      pf[c * 2]     = p[0];
      pf[c * 2 + 1] = p[1];
    }
  };

  const int kcBeg = half * 36, kcEnd = kcBeg + 36;

  // prologue: gather + combine + stage chunk kcBeg into buffer 0
  issue(kcBeg);
  {
    const float* pfp = (const float*)pf;
    short8 hv, lv;
#pragma unroll
    for (int j = 0; j < 8; ++j) {
      float v = w4[0] * pfp[j] + w4[1] * pfp[8 + j] + w4[2] * pfp[16 + j] +
                w4[3] * pfp[24 + j];
      short hh, ll; split_bf16(v, hh, ll);
      hv[j] = hh; lv[j] = ll;
    }
    *(short8*)&Ah[0][awoff] = hv;
    *(short8*)&Al[0][awoff] = lv;
  }
  __syncthreads();

  int cur = 0;
  for (int kc = kcBeg; kc < kcEnd; ++kc) {
    if (kc + 1 < kcEnd) issue(kc + 1);   // gathers fly under the MFMA phase

    short8 ah[4], al[4], bh[4], bl[4];
#pragma unroll
    for (int ni = 0; ni < 4; ++ni) {
      int bidx = (kc * 16 + wv * 4 + ni) * 64 + lane;
      bh[ni] = BH[bidx];
      bl[ni] = BL[bidx];
    }
#pragma unroll
    for (int mi = 0; mi < 4; ++mi) {
      ah[mi] = *(const short8*)&Ah[cur][(mi * 64 + lane) * 8];
      al[mi] = *(const short8*)&Al[cur][(mi * 64 + lane) * 8];
    }
#pragma unroll
    for (int mi = 0; mi < 4; ++mi)
#pragma unroll
      for (int ni = 0; ni < 4; ++ni) {
        acc[mi][ni] = __builtin_amdgcn_mfma_f32_16x16x32_bf16(ah[mi], bh[ni], acc[mi][ni], 0, 0, 0);
        acc[mi][ni] = __builtin_amdgcn_mfma_f32_16x16x32_bf16(ah[mi], bl[ni], acc[mi][ni], 0, 0, 0);
        acc[mi][ni] = __builtin_amdgcn_mfma_f32_16x16x32_bf16(al[mi], bh[ni], acc[mi][ni], 0, 0, 0);
      }

    if (kc + 1 < kcEnd) {               // combine + stage next chunk, other buffer
      const float* pfp = (const float*)pf;
      short8 hv, lv;
#pragma unroll
      for (int j = 0; j < 8; ++j) {
        float v = w4[0] * pfp[j] + w4[1] * pfp[8 + j] + w4[2] * pfp[16 + j] +
                  w4[3] * pfp[24 + j];
        short hh, ll; split_bf16(v, hh, ll);
        hv[j] = hh; lv[j] = ll;
      }
      *(short8*)&Ah[cur ^ 1][awoff] = hv;
      *(short8*)&Al[cur ^ 1][awoff] = lv;
    }
    __syncthreads();                    // single barrier per chunk
    cur ^= 1;
  }

  // epilogue: use the MEASURED C/D map -> NHWC fp32 partial for this K-half
  float* o = half ? out1 : out0;
#pragma unroll
  for (int mi = 0; mi < 4; ++mi)
#pragma unroll
    for (int ni = 0; ni < 4; ++ni)
#pragma unroll
      for (int r = 0; r < 4; ++r) {
        int pgx = pbase + mi * 16 + rowmap[r];
        o[pgx * 256 + wv * 64 + ni * 16 + colmap[r]] = acc[mi][ni][r];
      }
}

// ---------------- launcher ----------------
extern "C" void kernel_launch(void* const* d_in, const int* in_sizes, int n_in,
                              void* d_out, int out_size, void* d_ws, size_t ws_size,
                              hipStream_t stream) {
  const float* x  = (const float*)d_in[0];
  const float* y  = (const float*)d_in[1];
  const float* ow = (const float*)d_in[2];   // [4][18][256][3][3]
  const float* dw = (const float*)d_in[3];   // [3][256][256][3][3]
  float* out = (float*)d_out;

  float* fA      = (float*)d_ws;
  float* fB      = fA + FEAT_N;
  float* off_buf = fB + FEAT_N;
  float* wto     = off_buf + OFF_N;          // 4 * WTO_L fp32
  unsigned short* wbh = (unsigned short*)(wto + 4 * WTO_L);
  unsigned short* wbl = wbh + 3 * WB_L;
  float* pscr    = (float*)(wbl + 3 * WB_L); // deform K-half-1 partial (FEAT_N)
  float* oscr1   = pscr + FEAT_N;            // off_conv K-third-1 partial (OFF_N)
  float* oscr2   = oscr1 + OFF_N;            // off_conv K-third-2 partial (OFF_N)
  // total ~62 MB; ws_size >= ~93 MB proven by R10's NQ=4 run.

  concat_nhwc<<<dim3(1024), dim3(256), 0, stream>>>(x, y, fA);
  prep_wb<<<dim3(3 * WB_L / 256), dim3(256), 0, stream>>>(dw, wbh, wbl);
  t_ow<<<dim3(4 * WTO_L / 256), dim3(256), 0, stream>>>(ow, wto);

  float* cur = fA;
  float* nxt = fB;
  for (int i = 0; i < 3; ++i) {
    off_conv<false><<<dim3(768), dim3(512), 0, stream>>>(cur, wto + i * WTO_L,
                                                         off_buf, oscr1, oscr2);
    addf2o<<<dim3(OFF_N / 4 / 256), dim3(256), 0, stream>>>(off_buf, oscr1,
                                                            oscr2);
    deform_mfma<<<dim3(512), dim3(256), 0, stream>>>(
        cur, off_buf, wbh + i * WB_L, wbl + i * WB_L, nxt, pscr);
    addf<<<dim3(FEAT_N / 4 / 256), dim3(256), 0, stream>>>(nxt, pscr);
    float* tmp = cur; cur = nxt; nxt = tmp;
  }
  off_conv<true><<<dim3(768), dim3(512), 0, stream>>>(cur, wto + 3 * WTO_L, out,
                                                      oscr1, oscr2);
  addf2o<<<dim3(OFF_N / 4 / 256), dim3(256), 0, stream>>>(out, oscr1, oscr2);
}

// Round 17
// 463.684 us; speedup vs baseline: 1.1373x; 1.0159x over previous
//
#include <hip/hip_runtime.h>

typedef short short8 __attribute__((ext_vector_type(8)));
typedef float floatx4 __attribute__((ext_vector_type(4)));

constexpr int N_PIX  = 16384;           // 4*64*64 pixels
constexpr int FEAT_N = N_PIX * 256;     // floats per feat buffer
constexpr int OFF_N  = N_PIX * 18;
constexpr int KDIM   = 2304;
constexpr int WB_L   = 2304 * 256;      // bf16 elems per deform layer
constexpr int WTO_L  = KDIM * 18;       // fp32 elems per offset layer

__device__ __forceinline__ unsigned short bf16_rn(float v) {
  unsigned u = __float_as_uint(v);
  return (unsigned short)((u + 0x7FFFu + ((u >> 16) & 1u)) >> 16);
}
__device__ __forceinline__ void split_bf16(float v, short& h, short& l) {
  unsigned short hu = bf16_rn(v);
  float hf = __uint_as_float(((unsigned)hu) << 16);
  h = (short)hu;
  l = (short)bf16_rn(v - hf);
}

// ---------------- concat [x;y] NCHW -> feat NHWC (fp32) ----------------
__global__ __launch_bounds__(256) void concat_nhwc(const float* __restrict__ x,
                                                   const float* __restrict__ y,
                                                   float* __restrict__ feat) {
  __shared__ float tile[64][65];
  int bid = blockIdx.x;                 // b*256 + h*4 + ct
  int ct = bid & 3, h = (bid >> 2) & 63, b = bid >> 8;
  int c0 = ct * 64;
  const float* src = (c0 < 128) ? x : y;
  int cs = c0 & 127;
  int t = threadIdx.x;
  int w = t & 63, cl = t >> 6;
#pragma unroll
  for (int i = 0; i < 16; ++i) {
    int c = cl + i * 4;
    tile[c][w] = src[((b * 128 + cs + c) * 64 + h) * 64 + w];
  }
  __syncthreads();
  int c2 = t & 63, wl = t >> 6;
#pragma unroll
  for (int i = 0; i < 16; ++i) {
    int w2 = wl + i * 4;
    feat[((b * 64 + h) * 64 + w2) * 256 + c0 + c2] = tile[c2][w2];
  }
}

// ------------- weight prep: deform_w -> MFMA-fragment-linear hi/lo bf16 -------------
__global__ __launch_bounds__(256) void prep_wb(const float* __restrict__ dw,
                                               unsigned short* __restrict__ wbh,
                                               unsigned short* __restrict__ wbl) {
  int g = blockIdx.x * 256 + threadIdx.x;      // < 3*WB_L
  int l = g / WB_L, r = g % WB_L;
  int j = r & 7, lane = (r >> 3) & 63, nt = (r >> 9) & 15, kc = r >> 13;
  int k = kc * 32 + (lane >> 4) * 8 + j;
  int o = nt * 16 + (lane & 15);
  float w = dw[((l * 256 + o) * 256 + (k & 255)) * 9 + (k >> 8)];
  short h, lo; split_bf16(w, h, lo);
  wbh[g] = (unsigned short)h; wbl[g] = (unsigned short)lo;
}

// offset_w [4][18(o)][256(i)][3][3] -> wto[l][(tap*256+i)*18 + o]  (fp32)
__global__ __launch_bounds__(256) void t_ow(const float* __restrict__ ow,
                                            float* __restrict__ wto) {
  int g = blockIdx.x * 256 + threadIdx.x;      // < 4*41472
  int l = g / WTO_L, r = g % WTO_L;
  int o = r % 18, k = r / 18;
  int i = k & 255, tap = k >> 8;
  wto[g] = ow[(l * 18 + o) * KDIM + i * 9 + tap];
}

// ---------------- partial-sum folds (float4) ----------------
__global__ __launch_bounds__(256) void addf(float* __restrict__ a,
                                            const float* __restrict__ b) {
  int i = (blockIdx.x * 256 + threadIdx.x) * 4;
  float4 va = *(const float4*)(a + i);
  float4 vb = *(const float4*)(b + i);
  va.x += vb.x; va.y += vb.y; va.z += vb.z; va.w += vb.w;
  *(float4*)(a + i) = va;
}
__global__ __launch_bounds__(256) void addf2o(float* __restrict__ a,
                                              const float* __restrict__ b,
                                              const float* __restrict__ c) {
  int i = (blockIdx.x * 256 + threadIdx.x) * 4;
  float4 va = *(const float4*)(a + i);
  float4 vb = *(const float4*)(b + i);
  float4 vc = *(const float4*)(c + i);
  va.x += vb.x + vc.x; va.y += vb.y + vc.y;
  va.z += vb.z + vc.z; va.w += vb.w + vc.w;
  *(float4*)(a + i) = va;
}

// ---------------- offset conv (3x3 SAME, 256 -> 18) — K-split x3 (R14/R15-verified) ----
template <bool NCHW>
__global__ __launch_bounds__(512) void off_conv(const float* __restrict__ feat,
                                                const float* __restrict__ wo,
                                                float* __restrict__ o0,
                                                float* __restrict__ o1,
                                                float* __restrict__ o2) {
  __shared__ float red[512][19];
  int t = threadIdx.x;
  int lane = t & 63;
  int wid = __builtin_amdgcn_readfirstlane(t >> 6);   // wave 0..7
  const int r_  = blockIdx.x & 255;
  const int pg  = (r_ & 7) * 32 + (r_ >> 3);          // XCD-chunked, bijective
  const int third = blockIdx.x >> 8;                  // K-third
  int p = pg * 64 + lane;
  int b = p >> 12, h = (p >> 6) & 63, w = p & 63;
  float acc[18] = {};
  const int cb = (third * 8 + wid) * 6;
  for (int kc = cb; kc < cb + 6; ++kc) {
    int k0 = kc * 16;
    int tap = k0 >> 8, c0 = k0 & 255;
    int y = h + tap / 3 - 1, xx = w + tap % 3 - 1;
    float a[16];
#pragma unroll
    for (int q = 0; q < 16; ++q) a[q] = 0.f;
    if ((unsigned)y < 64u && (unsigned)xx < 64u) {
      const float4* srcp =
          (const float4*)(feat + ((b * 64 + y) * 64 + xx) * 256 + c0);
#pragma unroll
      for (int q = 0; q < 4; ++q) {
        float4 v = srcp[q];
        a[q * 4 + 0] = v.x; a[q * 4 + 1] = v.y;
        a[q * 4 + 2] = v.z; a[q * 4 + 3] = v.w;
      }
    }
    const float* wp = wo + k0 * 18;   // wave-uniform -> scalar loads
#pragma unroll
    for (int kk = 0; kk < 16; ++kk)
#pragma unroll
      for (int o = 0; o < 18; ++o)
        acc[o] += a[kk] * wp[kk * 18 + o];
  }
#pragma unroll
  for (int o = 0; o < 18; ++o) red[t][o] = acc[o];
  __syncthreads();
  if (t < 64) {
    float* outp = (third == 0) ? o0 : (third == 1 ? o1 : o2);
#pragma unroll
    for (int o = 0; o < 18; ++o) {
      float s = 0.f;
#pragma unroll
      for (int sg = 0; sg < 8; ++sg) s += red[lane + 64 * sg][o];
      if (NCHW)
        outp[(b * 18 + o) * 4096 + (p & 4095)] = s;
      else
        outp[p * 18 + o] = s;
    }
  }
}

// ---------------- deform conv — R12/R15 ping-pong + fused off-fold + setprio ----
// vs R15: (1) coord phase reads the three off_conv partials and sums them
// o0 + (o1 + o2) — the exact adds addf2o performed, same order, before the same
// use -> bit-identical; the 3 addf2o dispatches between off_conv and deform are
// dropped. (2) s_setprio(1/0) brackets the MFMA cluster (scheduler hint only,
// zero arithmetic change; helps when the 2 co-resident blocks are phase-offset).
__global__ __launch_bounds__(256) void deform_mfma(
    const float* __restrict__ feat,
    const float* __restrict__ o0, const float* __restrict__ o1,
    const float* __restrict__ o2,
    const unsigned short* __restrict__ wbh, const unsigned short* __restrict__ wbl,
    float* __restrict__ out0, float* __restrict__ out1) {
  __shared__ __align__(16) unsigned short Ah[2][64 * 32], Al[2][64 * 32];
  __shared__ float cy[9][64], cx[9][64];
  const int t = threadIdx.x;
  const int r_  = blockIdx.x & 255;
  const int pg  = (r_ & 7) * 32 + (r_ >> 3);   // XCD-chunked, bijective on [0,256)
  const int pbase = pg * 64;
  const int half  = blockIdx.x >> 8;           // K-half: chunks [36h, 36h+36)
  const int bimg = pbase >> 12, h = (pbase >> 6) & 63;
  const float* fbase = feat + bimg * (4096 * 256);

  {  // sampling coords per (tap, pixel); off field = o0 + (o1 + o2) (addf2o order)
    int m = t & 63, p = pbase + m;
    for (int tap = t >> 6; tap < 9; tap += 4) {
      int iy = p * 18 + 2 * tap, ix = iy + 1;
      float oy = o0[iy] + (o1[iy] + o2[iy]);
      float ox = o0[ix] + (o1[ix] + o2[ix]);
      cy[tap][m] = oy + (float)(tap / 3 - 1 + h);
      cx[tap][m] = ox + (float)(tap % 3 - 1 + m);
    }
  }
  __syncthreads();

  const int m  = t & 63;                       // gather pixel
  const int cg = t >> 6;                       // gather channel-group (8 ch)
  const int lane = t & 63;
  const int wv = __builtin_amdgcn_readfirstlane(t >> 6);
  const int awoff = ((m >> 4) * 64 + cg * 16 + (m & 15)) * 8;  // frag-linear A slot

  floatx4 acc[4][4];
  const floatx4 z4 = {0.f, 0.f, 0.f, 0.f};
#pragma unroll
  for (int i = 0; i < 4; ++i)
#pragma unroll
    for (int jn = 0; jn < 4; ++jn) acc[i][jn] = z4;

  // ---- calibration MFMA: measure the true C/D slot map ----
  int rowmap[4], colmap[4];
  {
    short8 cA, cB;
    int own = lane & 15, q = (lane >> 4) & 3;
#pragma unroll
    for (int j = 0; j < 8; ++j) {
      int k = q * 8 + j;                     // assumed k-slot id (shared-perm safe)
      cA[j] = (short)((k == own) ? bf16_rn(1.0f) : 0);
      cB[j] = (short)((k < 16) ? bf16_rn((float)(k * 16 + own)) : 0);
    }
    floatx4 cal = __builtin_amdgcn_mfma_f32_16x16x32_bf16(cA, cB, z4, 0, 0, 0);
#pragma unroll
    for (int r = 0; r < 4; ++r) {
      int v = (int)(cal[r] + 0.5f);          // exact integer in [0,255]
      rowmap[r] = (v >> 4) & 15;
      colmap[r] = v & 15;
    }
  }

  const short8* BH = (const short8*)wbh;
  const short8* BL = (const short8*)wbl;

  float4 pf[8];
  float w4[4];
  auto issue = [&](int kc) {
    int tap = kc >> 3, c0 = (kc & 7) * 32 + cg * 8;
    float py = cy[tap][m], px = cx[tap][m];
    float fy = floorf(py), fx = floorf(px);
    int iy = (int)fy, ix = (int)fx;
    float wy1 = py - fy, wx1 = px - fx;
    float wy0 = 1.f - wy1, wx0 = 1.f - wx1;
    w4[0] = wy0 * wx0; w4[1] = wy0 * wx1; w4[2] = wy1 * wx0; w4[3] = wy1 * wx1;
#pragma unroll
    for (int c = 0; c < 4; ++c) {
      int yy = iy + (c >> 1), xx = ix + (c & 1);
      bool ok = ((unsigned)yy < 64u) && ((unsigned)xx < 64u);
      if (!ok) w4[c] = 0.f;
      int yc = min(max(yy, 0), 63), xc = min(max(xx, 0), 63);
      const float4* p = (const float4*)(fbase + (yc * 64 + xc) * 256 + c0);
      pf[c * 2]     = p[0];
      pf[c * 2 + 1] = p[1];
    }
  };

  const int kcBeg = half * 36, kcEnd = kcBeg + 36;

  // prologue: gather + combine + stage chunk kcBeg into buffer 0
  issue(kcBeg);
  {
    const float* pfp = (const float*)pf;
    short8 hv, lv;
#pragma unroll
    for (int j = 0; j < 8; ++j) {
      float v = w4[0] * pfp[j] + w4[1] * pfp[8 + j] + w4[2] * pfp[16 + j] +
                w4[3] * pfp[24 + j];
      short hh, ll; split_bf16(v, hh, ll);
      hv[j] = hh; lv[j] = ll;
    }
    *(short8*)&Ah[0][awoff] = hv;
    *(short8*)&Al[0][awoff] = lv;
  }
  __syncthreads();

  int cur = 0;
  for (int kc = kcBeg; kc < kcEnd; ++kc) {
    if (kc + 1 < kcEnd) issue(kc + 1);   // gathers fly under the MFMA phase

    short8 ah[4], al[4], bh[4], bl[4];
#pragma unroll
    for (int ni = 0; ni < 4; ++ni) {
      int bidx = (kc * 16 + wv * 4 + ni) * 64 + lane;
      bh[ni] = BH[bidx];
      bl[ni] = BL[bidx];
    }
#pragma unroll
    for (int mi = 0; mi < 4; ++mi) {
      ah[mi] = *(const short8*)&Ah[cur][(mi * 64 + lane) * 8];
      al[mi] = *(const short8*)&Al[cur][(mi * 64 + lane) * 8];
    }
    __builtin_amdgcn_s_setprio(1);
#pragma unroll
    for (int mi = 0; mi < 4; ++mi)
#pragma unroll
      for (int ni = 0; ni < 4; ++ni) {
        acc[mi][ni] = __builtin_amdgcn_mfma_f32_16x16x32_bf16(ah[mi], bh[ni], acc[mi][ni], 0, 0, 0);
        acc[mi][ni] = __builtin_amdgcn_mfma_f32_16x16x32_bf16(ah[mi], bl[ni], acc[mi][ni], 0, 0, 0);
        acc[mi][ni] = __builtin_amdgcn_mfma_f32_16x16x32_bf16(al[mi], bh[ni], acc[mi][ni], 0, 0, 0);
      }
    __builtin_amdgcn_s_setprio(0);

    if (kc + 1 < kcEnd) {               // combine + stage next chunk, other buffer
      const float* pfp = (const float*)pf;
      short8 hv, lv;
#pragma unroll
      for (int j = 0; j < 8; ++j) {
        float v = w4[0] * pfp[j] + w4[1] * pfp[8 + j] + w4[2] * pfp[16 + j] +
                  w4[3] * pfp[24 + j];
        short hh, ll; split_bf16(v, hh, ll);
        hv[j] = hh; lv[j] = ll;
      }
      *(short8*)&Ah[cur ^ 1][awoff] = hv;
      *(short8*)&Al[cur ^ 1][awoff] = lv;
    }
    __syncthreads();                    // single barrier per chunk
    cur ^= 1;
  }

  // epilogue: use the MEASURED C/D map -> NHWC fp32 partial for this K-half
  float* o = half ? out1 : out0;
#pragma unroll
  for (int mi = 0; mi < 4; ++mi)
#pragma unroll
    for (int ni = 0; ni < 4; ++ni)
#pragma unroll
      for (int r = 0; r < 4; ++r) {
        int pgx = pbase + mi * 16 + rowmap[r];
        o[pgx * 256 + wv * 64 + ni * 16 + colmap[r]] = acc[mi][ni][r];
      }
}

// ---------------- launcher ----------------
extern "C" void kernel_launch(void* const* d_in, const int* in_sizes, int n_in,
                              void* d_out, int out_size, void* d_ws, size_t ws_size,
                              hipStream_t stream) {
  const float* x  = (const float*)d_in[0];
  const float* y  = (const float*)d_in[1];
  const float* ow = (const float*)d_in[2];   // [4][18][256][3][3]
  const float* dw = (const float*)d_in[3];   // [3][256][256][3][3]
  float* out = (float*)d_out;

  float* fA      = (float*)d_ws;
  float* fB      = fA + FEAT_N;
  float* off_buf = fB + FEAT_N;
  float* wto     = off_buf + OFF_N;          // 4 * WTO_L fp32
  unsigned short* wbh = (unsigned short*)(wto + 4 * WTO_L);
  unsigned short* wbl = wbh + 3 * WB_L;
  float* pscr    = (float*)(wbl + 3 * WB_L); // deform K-half-1 partial (FEAT_N)
  float* oscr1   = pscr + FEAT_N;            // off_conv K-third-1 partial (OFF_N)
  float* oscr2   = oscr1 + OFF_N;            // off_conv K-third-2 partial (OFF_N)
  // total ~62 MB; ws_size >= ~93 MB proven by R10's NQ=4 run.

  concat_nhwc<<<dim3(1024), dim3(256), 0, stream>>>(x, y, fA);
  prep_wb<<<dim3(3 * WB_L / 256), dim3(256), 0, stream>>>(dw, wbh, wbl);
  t_ow<<<dim3(4 * WTO_L / 256), dim3(256), 0, stream>>>(ow, wto);

  float* cur = fA;
  float* nxt = fB;
  for (int i = 0; i < 3; ++i) {
    off_conv<false><<<dim3(768), dim3(512), 0, stream>>>(cur, wto + i * WTO_L,
                                                         off_buf, oscr1, oscr2);
    deform_mfma<<<dim3(512), dim3(256), 0, stream>>>(
        cur, off_buf, oscr1, oscr2, wbh + i * WB_L, wbl + i * WB_L, nxt, pscr);
    addf<<<dim3(FEAT_N / 4 / 256), dim3(256), 0, stream>>>(nxt, pscr);
    float* tmp = cur; cur = nxt; nxt = tmp;
  }
  off_conv<true><<<dim3(768), dim3(512), 0, stream>>>(cur, wto + 3 * WTO_L, out,
                                                      oscr1, oscr2);
  addf2o<<<dim3(OFF_N / 4 / 256), dim3(256), 0, stream>>>(out, oscr1, oscr2);
}